// Round 10
// baseline (106.438 us; speedup 1.0000x reference)
//
#include <hip/hip_runtime.h>
#include <hip/hip_bf16.h>

// NeuralGraphOutput: out[b,o] = sum_a mask[b,a] * relu( sum_f x[b,a,f] * W[f,o] + bias[o] )
//   x[b,a,:] = concat(atoms[b,a,0:64], sum_d bonds[b,a,d,0:16])   (80 features)
//   mask[b,a] = any(edges[b,a,d] != -1)
// B=2048, A=256, D=8, FA=64, FB=16, FP=256
//
// R10: quarter-molecule blocks (8192 x 256 thr, AH=64, LDS 13.1KB) — halve the
// phase quantum again (R2->R4 halving gave 154->90us; R4..R9 plateau at ~89us
// diagnosed as too-coarse stage/compute interleave at 4-5 blocks/CU; now ~6
// blocks/CU and half the barrier quantum). Epilogue fused: memsetAsync(out,0)
// + per-block atomicAdd (4 fp32 contributions/element, sub-ulp reorder noise
// only) — removes the reduce kernel, a launch gap, and 10MB of part traffic.
//  - R9 burst staging kept (halved: 8 bonds float4 + 4 atoms float4 + edges).
//  - W pre-swizzled fragments loaded after staging, before barrier (R5/R9).

#define NB 2048
#define NA 256
#define ND 8
#define NFA 64
#define NFB 16
#define NF 80
#define NFP 256
#define PITCH 100          // bf16 elems per LDS row (200B stride: conflict-free b128)
#define AH 64              // atoms per block (quarter molecule)

typedef __attribute__((ext_vector_type(8))) short short8;   // 8 bf16 = 4 VGPR
typedef __attribute__((ext_vector_type(4))) float f32x4;    // MFMA C/D

static __device__ __forceinline__ unsigned int pk2bf(float lo, float hi) {
    // packed RNE fp32->bf16 pair; compiler emits v_cvt_pk_bf16_f32
    __hip_bfloat162 h = __float22bfloat162_rn(float2{lo, hi});
    return *reinterpret_cast<unsigned int*>(&h);
}

static __device__ __forceinline__ unsigned short f2bf(float f) {
    unsigned int u = __float_as_uint(f);
    return (unsigned short)((u + 0x7FFFu + ((u >> 16) & 1u)) >> 16);
}

// ---------- prep: W[80][256] fp32 -> bf16 B-fragments [ntg][ks][lane] ----------
__global__ void ngf_prep_w(const float* __restrict__ W, short8* __restrict__ wfrag)
{
    const int gid  = blockIdx.x;        // 0..47 = ntg*3 + ks
    const int nt   = gid / 3;
    const int ks   = gid % 3;
    const int lane = threadIdx.x;       // 0..63
    const int c    = nt * 16 + (lane & 15);
    short8 v;
    #pragma unroll
    for (int j = 0; j < 8; ++j) {
        const int k = ks * 32 + (lane >> 4) * 8 + j;
        float w = (k < NF) ? W[k * NFP + c] : 0.0f;
        v[j] = (short)f2bf(w);
    }
    wfrag[gid * 64 + lane] = v;
}

// ---------- main: quarter molecule per block ----------
__launch_bounds__(256, 4)
__global__ void ngf_mfma_kernel(const float4* __restrict__ atoms4,
                                const float4* __restrict__ bonds4,
                                const int4*   __restrict__ edges4,
                                const short8* __restrict__ wfrag,
                                const float*  __restrict__ bias,
                                float* __restrict__ out)
{
    const int bid  = blockIdx.x;         // 0..8191
    const int tid  = threadIdx.x;        // 0..255
    const int wave = tid >> 6;           // 0..3
    const int lane = tid & 63;
    const int lrow = lane & 15;          // A row / B col / C-D col
    const int lgrp = lane >> 4;          // k-group (A/B) / row-group (C/D)

    __shared__ unsigned short X[AH * PITCH];   // 12800 B
    __shared__ float maskf[AH];                // 256 B

    const size_t atomBase = (size_t)bid * AH;  // == mol*256 + quarter*64

    // ================= staging: burst-issue all loads first =================
    const int ba = tid >> 2;            // bonds atom 0..63
    const int q  = tid & 3;             // quarter of the 16-fb row
    const float4* bp = bonds4 + (atomBase + ba) * 32 + q;   // atom row = 32 float4

    float4 bv[8];
    #pragma unroll
    for (int d = 0; d < 8; ++d) bv[d] = bp[d * 4];

    float4 av[4];
    #pragma unroll
    for (int it = 0; it < 4; ++it) {
        const int flat = it * 256 + tid;
        av[it] = atoms4[(atomBase + (flat >> 4)) * 16 + (flat & 15)];
    }

    int4 e0, e1;
    if (tid < AH) {
        e0 = edges4[(atomBase + tid) * 2];
        e1 = edges4[(atomBase + tid) * 2 + 1];
    }

    // ---------------- process (vmcnt-ordered: bonds complete first) ----------
    {   // bonds d-sum -> X[ba][64 + q*4 .. +3]
        float4 s = {0.0f, 0.0f, 0.0f, 0.0f};
        #pragma unroll
        for (int d = 0; d < 8; ++d) { s.x += bv[d].x; s.y += bv[d].y; s.z += bv[d].z; s.w += bv[d].w; }
        uint2 o; o.x = pk2bf(s.x, s.y); o.y = pk2bf(s.z, s.w);
        *(uint2*)&X[ba * PITCH + NFA + q * 4] = o;
    }
    // atoms
    #pragma unroll
    for (int it = 0; it < 4; ++it) {
        const int flat = it * 256 + tid;
        const int a = flat >> 4, k4 = flat & 15;
        uint2 o; o.x = pk2bf(av[it].x, av[it].y); o.y = pk2bf(av[it].z, av[it].w);
        *(uint2*)&X[a * PITCH + k4 * 4] = o;
    }
    // mask + K pad (k=80..95)
    if (tid < AH) {
        bool any = (e0.x != -1) | (e0.y != -1) | (e0.z != -1) | (e0.w != -1)
                 | (e1.x != -1) | (e1.y != -1) | (e1.z != -1) | (e1.w != -1);
        maskf[tid] = any ? 1.0f : 0.0f;
        uint4 z = {0u, 0u, 0u, 0u};
        *(uint4*)&X[tid * PITCH + 80] = z;
        *(uint4*)&X[tid * PITCH + 88] = z;
    }

    // ---------- W fragments: once per block, overlaps barrier wait ----------
    short8 bf[3][4];
    float  bia[4];
    #pragma unroll
    for (int nt = 0; nt < 4; ++nt) {
        const int ntg = wave * 4 + nt;
        bia[nt] = bias[ntg * 16 + lrow];
        #pragma unroll
        for (int ks = 0; ks < 3; ++ks)
            bf[ks][nt] = wfrag[(ntg * 3 + ks) * 64 + lane];
    }
    __syncthreads();

    // ---------- compute: 4 strips of 16 atoms; wave owns 64 output cols ----------
    float colsum[4] = {0.0f, 0.0f, 0.0f, 0.0f};
    #pragma unroll
    for (int s = 0; s < 4; ++s) {
        const int row = s * 16 + lrow;
        const unsigned short* xr = &X[row * PITCH + lgrp * 8];
        short8 a0 = *(const short8*)(xr);          // k  0..31
        short8 a1 = *(const short8*)(xr + 32);     // k 32..63
        short8 a2 = *(const short8*)(xr + 64);     // k 64..95 (pad zeros)
        float4 m4 = *(const float4*)&maskf[s * 16 + lgrp * 4];
        #pragma unroll
        for (int nt = 0; nt < 4; ++nt) {
            f32x4 acc = {0.0f, 0.0f, 0.0f, 0.0f};
            acc = __builtin_amdgcn_mfma_f32_16x16x32_bf16(a0, bf[0][nt], acc, 0, 0, 0);
            acc = __builtin_amdgcn_mfma_f32_16x16x32_bf16(a1, bf[1][nt], acc, 0, 0, 0);
            acc = __builtin_amdgcn_mfma_f32_16x16x32_bf16(a2, bf[2][nt], acc, 0, 0, 0);
            const float bv2 = bia[nt];
            colsum[nt] += fmaxf(acc[0] + bv2, 0.0f) * m4.x
                        + fmaxf(acc[1] + bv2, 0.0f) * m4.y
                        + fmaxf(acc[2] + bv2, 0.0f) * m4.z
                        + fmaxf(acc[3] + bv2, 0.0f) * m4.w;
        }
    }

    // ---------- reduce row-groups, atomic-accumulate into out ----------
    const int mol = bid >> 2;
    #pragma unroll
    for (int nt = 0; nt < 4; ++nt) {
        float v = colsum[nt];
        v += __shfl_xor(v, 16, 64);
        v += __shfl_xor(v, 32, 64);
        if (lane < 16)
            atomicAdd(&out[(size_t)mol * NFP + (wave * 4 + nt) * 16 + lane], v);
    }
}

extern "C" void kernel_launch(void* const* d_in, const int* in_sizes, int n_in,
                              void* d_out, int out_size, void* d_ws, size_t ws_size,
                              hipStream_t stream) {
    const float4* atoms4 = (const float4*)d_in[0];
    const float4* bonds4 = (const float4*)d_in[1];
    const int4*   edges4 = (const int4*)d_in[2];
    const float*  W      = (const float*)d_in[3];
    const float*  bias   = (const float*)d_in[4];
    float* out = (float*)d_out;

    short8* wfrag = (short8*)d_ws;

    hipMemsetAsync(d_out, 0, (size_t)out_size * sizeof(float), stream);
    ngf_prep_w<<<48, 64, 0, stream>>>(W, wfrag);
    ngf_mfma_kernel<<<NB * 4, 256, 0, stream>>>(atoms4, bonds4, edges4, wfrag, bias, out);
}

// Round 11
// 84.789 us; speedup vs baseline: 1.2553x; 1.2553x over previous
//
#include <hip/hip_runtime.h>
#include <hip/hip_bf16.h>

// NeuralGraphOutput: out[b,o] = sum_a mask[b,a] * relu( sum_f x[b,a,f] * W[f,o] + bias[o] )
//   x[b,a,:] = concat(atoms[b,a,0:64], sum_d bonds[b,a,d,0:16])   (80 features)
//   mask[b,a] = any(edges[b,a,d] != -1)
// B=2048, A=256, D=8, FA=64, FB=16, FP=256
//
// R11 = R9 main kernel (best: 88.5us) + fused epilogue:
//  - prep kernel also zeroes `out` (256 blocks; blocks 0..47 build wfrag)
//  - main kernel atomicAdds its reduced column sums straight into out
//    (2 contributions/element at AH=128; IEEE add is commutative -> exact,
//    deterministic). Removes the reduce dispatch + launch gap + 8MB partials.
//  - R10 lesson: AH=64 doubled per-block W-frag overhead; stay at AH=128.

#define NB 2048
#define NA 256
#define ND 8
#define NFA 64
#define NFB 16
#define NF 80
#define NFP 256
#define PITCH 100          // bf16 elems per LDS row (200B stride: conflict-free b128)
#define AH 128             // atoms per block (half molecule)

typedef __attribute__((ext_vector_type(8))) short short8;   // 8 bf16 = 4 VGPR
typedef __attribute__((ext_vector_type(4))) float f32x4;    // MFMA C/D

static __device__ __forceinline__ unsigned int pk2bf(float lo, float hi) {
    // packed RNE fp32->bf16 pair; compiler emits v_cvt_pk_bf16_f32
    __hip_bfloat162 h = __float22bfloat162_rn(float2{lo, hi});
    return *reinterpret_cast<unsigned int*>(&h);
}

static __device__ __forceinline__ unsigned short f2bf(float f) {
    unsigned int u = __float_as_uint(f);
    return (unsigned short)((u + 0x7FFFu + ((u >> 16) & 1u)) >> 16);
}

// ---------- prep: build W B-fragments (blocks 0..47) + zero out (all blocks) ----------
__global__ void ngf_prep_w(const float* __restrict__ W, short8* __restrict__ wfrag,
                           float4* __restrict__ out4)
{
    const int blk  = blockIdx.x;        // 0..255
    const int lane = threadIdx.x;       // 0..63

    // zero out: 2048*256 floats = 131072 float4; 16384 threads * 8 float4 each
    const int zbase = (blk * 64 + lane) * 8;
    #pragma unroll
    for (int i = 0; i < 8; ++i)
        out4[zbase + i] = float4{0.0f, 0.0f, 0.0f, 0.0f};

    if (blk < 48) {
        const int nt = blk / 3;
        const int ks = blk % 3;
        const int c  = nt * 16 + (lane & 15);
        short8 v;
        #pragma unroll
        for (int j = 0; j < 8; ++j) {
            const int k = ks * 32 + (lane >> 4) * 8 + j;
            float w = (k < NF) ? W[k * NFP + c] : 0.0f;
            v[j] = (short)f2bf(w);
        }
        wfrag[blk * 64 + lane] = v;
    }
}

// ---------- main: half molecule per block ----------
__launch_bounds__(256, 4)
__global__ void ngf_mfma_kernel(const float4* __restrict__ atoms4,
                                const float4* __restrict__ bonds4,
                                const int4*   __restrict__ edges4,
                                const short8* __restrict__ wfrag,
                                const float*  __restrict__ bias,
                                float* __restrict__ out)
{
    const int bid  = blockIdx.x;         // 0..4095
    const int tid  = threadIdx.x;        // 0..255
    const int wave = tid >> 6;           // 0..3
    const int lane = tid & 63;
    const int lrow = lane & 15;          // A row / B col / C-D col
    const int lgrp = lane >> 4;          // k-group (A/B) / row-group (C/D)

    __shared__ unsigned short X[AH * PITCH];   // 25600 B
    __shared__ float maskf[AH];                // 512 B

    const size_t atomBase = (size_t)bid * AH;  // == mol*256 + half*128

    // ================= staging: burst-issue ALL loads first =================
    const int ba = tid >> 2;            // bonds atom (pass0); pass1 = +64
    const int q  = tid & 3;             // quarter of the 16-fb row
    const float4* bp0 = bonds4 + (atomBase + ba) * 32 + q;        // row = 32 float4
    const float4* bp1 = bonds4 + (atomBase + 64 + ba) * 32 + q;

    float4 bv[16];
    #pragma unroll
    for (int d = 0; d < 8; ++d) bv[d] = bp0[d * 4];
    #pragma unroll
    for (int d = 0; d < 8; ++d) bv[8 + d] = bp1[d * 4];

    float4 av[8];
    #pragma unroll
    for (int it = 0; it < 8; ++it) {
        const int flat = it * 256 + tid;
        av[it] = atoms4[(atomBase + (flat >> 4)) * 16 + (flat & 15)];
    }

    // edges: all threads load (tid>=128 duplicates hit L1), store under mask
    const int ea = tid & 127;
    int4 e0 = edges4[(atomBase + ea) * 2];
    int4 e1 = edges4[(atomBase + ea) * 2 + 1];

    // ---------------- process (vmcnt-ordered: bonds complete first) ----------
    {   // bonds pass 0
        float4 s = {0.0f, 0.0f, 0.0f, 0.0f};
        #pragma unroll
        for (int d = 0; d < 8; ++d) { s.x += bv[d].x; s.y += bv[d].y; s.z += bv[d].z; s.w += bv[d].w; }
        uint2 o; o.x = pk2bf(s.x, s.y); o.y = pk2bf(s.z, s.w);
        *(uint2*)&X[ba * PITCH + NFA + q * 4] = o;
    }
    {   // bonds pass 1
        float4 s = {0.0f, 0.0f, 0.0f, 0.0f};
        #pragma unroll
        for (int d = 0; d < 8; ++d) { s.x += bv[8 + d].x; s.y += bv[8 + d].y; s.z += bv[8 + d].z; s.w += bv[8 + d].w; }
        uint2 o; o.x = pk2bf(s.x, s.y); o.y = pk2bf(s.z, s.w);
        *(uint2*)&X[(64 + ba) * PITCH + NFA + q * 4] = o;
    }
    // atoms
    #pragma unroll
    for (int it = 0; it < 8; ++it) {
        const int flat = it * 256 + tid;
        const int a = flat >> 4, k4 = flat & 15;
        uint2 o; o.x = pk2bf(av[it].x, av[it].y); o.y = pk2bf(av[it].z, av[it].w);
        *(uint2*)&X[a * PITCH + k4 * 4] = o;
    }
    // mask + K pad (k=80..95)
    if (tid < AH) {
        bool any = (e0.x != -1) | (e0.y != -1) | (e0.z != -1) | (e0.w != -1)
                 | (e1.x != -1) | (e1.y != -1) | (e1.z != -1) | (e1.w != -1);
        maskf[ea] = any ? 1.0f : 0.0f;
        uint4 z = {0u, 0u, 0u, 0u};
        *(uint4*)&X[ea * PITCH + 80] = z;
        *(uint4*)&X[ea * PITCH + 88] = z;
    }

    // ---------- W fragments: once per block, overlaps barrier wait ----------
    short8 bf[3][4];
    float  bia[4];
    #pragma unroll
    for (int nt = 0; nt < 4; ++nt) {
        const int ntg = wave * 4 + nt;
        bia[nt] = bias[ntg * 16 + lrow];
        #pragma unroll
        for (int ks = 0; ks < 3; ++ks)
            bf[ks][nt] = wfrag[(ntg * 3 + ks) * 64 + lane];
    }
    __syncthreads();

    // ---------- compute: 8 strips of 16 atoms; wave owns 64 output cols ----------
    float colsum[4] = {0.0f, 0.0f, 0.0f, 0.0f};
    #pragma unroll 2
    for (int s = 0; s < 8; ++s) {
        const int row = s * 16 + lrow;
        const unsigned short* xr = &X[row * PITCH + lgrp * 8];
        short8 a0 = *(const short8*)(xr);          // k  0..31
        short8 a1 = *(const short8*)(xr + 32);     // k 32..63
        short8 a2 = *(const short8*)(xr + 64);     // k 64..95 (pad zeros)
        float4 m4 = *(const float4*)&maskf[s * 16 + lgrp * 4];
        #pragma unroll
        for (int nt = 0; nt < 4; ++nt) {
            f32x4 acc = {0.0f, 0.0f, 0.0f, 0.0f};
            acc = __builtin_amdgcn_mfma_f32_16x16x32_bf16(a0, bf[0][nt], acc, 0, 0, 0);
            acc = __builtin_amdgcn_mfma_f32_16x16x32_bf16(a1, bf[1][nt], acc, 0, 0, 0);
            acc = __builtin_amdgcn_mfma_f32_16x16x32_bf16(a2, bf[2][nt], acc, 0, 0, 0);
            const float bv2 = bia[nt];
            colsum[nt] += fmaxf(acc[0] + bv2, 0.0f) * m4.x
                        + fmaxf(acc[1] + bv2, 0.0f) * m4.y
                        + fmaxf(acc[2] + bv2, 0.0f) * m4.z
                        + fmaxf(acc[3] + bv2, 0.0f) * m4.w;
        }
    }

    // ---------- reduce row-groups, atomic-accumulate into out ----------
    const int mol = bid >> 1;
    #pragma unroll
    for (int nt = 0; nt < 4; ++nt) {
        float v = colsum[nt];
        v += __shfl_xor(v, 16, 64);
        v += __shfl_xor(v, 32, 64);
        if (lane < 16)
            atomicAdd(&out[(size_t)mol * NFP + (wave * 4 + nt) * 16 + lane], v);
    }
}

extern "C" void kernel_launch(void* const* d_in, const int* in_sizes, int n_in,
                              void* d_out, int out_size, void* d_ws, size_t ws_size,
                              hipStream_t stream) {
    const float4* atoms4 = (const float4*)d_in[0];
    const float4* bonds4 = (const float4*)d_in[1];
    const int4*   edges4 = (const int4*)d_in[2];
    const float*  W      = (const float*)d_in[3];
    const float*  bias   = (const float*)d_in[4];
    float* out = (float*)d_out;

    short8* wfrag = (short8*)d_ws;

    ngf_prep_w<<<256, 64, 0, stream>>>(W, wfrag, (float4*)out);
    ngf_mfma_kernel<<<NB * 2, 256, 0, stream>>>(atoms4, bonds4, edges4, wfrag, bias, out);
}